// Round 14
// baseline (1449.944 us; speedup 1.0000x reference)
//
#include <hip/hip_runtime.h>

typedef unsigned short u16;
typedef __attribute__((ext_vector_type(8))) short s16x8;
typedef __attribute__((ext_vector_type(4))) float f32x4;

__device__ __forceinline__ float bf2f(u16 u) {
    union { unsigned i; float f; } v; v.i = (unsigned)u << 16; return v.f;
}
__device__ __forceinline__ u16 f2bf(float f) {
    union { float f; unsigned i; } v; v.f = f;
    unsigned r = v.i + 0x7fffu + ((v.i >> 16) & 1u);
    return (u16)(r >> 16);
}
__device__ __forceinline__ unsigned fbits(float f) {
    union { float f; unsigned i; } v; v.f = f; return v.i;
}
__device__ __forceinline__ f32x4 mfma16(s16x8 a, s16x8 b, f32x4 c) {
    return __builtin_amdgcn_mfma_f32_16x16x32_bf16(a, b, c, 0, 0, 0);
}

#define PLANE 4325376   // u16 elements per qkv plane: 128*8*264*16

// ---------------------------------------------------------------------------
// One-shot fp32 -> bf16 conversion of all constant tensors (6 segments, each
// a multiple of 256 elements -> block-aligned, fully coalesced).
// ---------------------------------------------------------------------------
__global__ __launch_bounds__(256)
void cvt_all(const float* __restrict__ Wqkv, const float* __restrict__ Wo,
             const float* __restrict__ W1, const float* __restrict__ W2,
             const float* __restrict__ cw, const float* __restrict__ x,
             u16* wq16, u16* wo16, u16* w116, u16* w216, u16* cw16, u16* x16)
{
    int i = blockIdx.x * 256 + threadIdx.x;           // < 5468160
    if (i < 589824)        wq16[i] = f2bf(Wqkv[i]);
    else if (i < 786432)   wo16[i - 589824] = f2bf(Wo[i - 589824]);
    else if (i < 1572864)  w116[i - 786432] = f2bf(W1[i - 786432]);
    else if (i < 2359296)  w216[i - 1572864] = f2bf(W2[i - 1572864]);
    else if (i < 2371584)  cw16[i - 2359296] = f2bf(cw[i - 2359296]);
    else                   x16[i - 2371584] = f2bf(x[i - 2371584]);
}

// ---------------------------------------------------------------------------
// cls rows: h[b, s<12, :] = cls[s] + pos[s]   (bf16 out only)
// ---------------------------------------------------------------------------
__global__ __launch_bounds__(256)
void embed_cls_kernel(const float* __restrict__ cls, const float* __restrict__ pos,
                      u16* __restrict__ h16)
{
    int i = blockIdx.x * 256 + threadIdx.x;           // < 128*12*128
    int e = i & 127, s = (i >> 7) % 12, b = i / (12 * 128);
    float v = cls[s * 128 + e] + pos[s * 128 + e];
    h16[((size_t)b * 264 + s) * 128 + e] = f2bf(v);
}

// ---------------------------------------------------------------------------
// Conv-embed via MFMA: rows = (b,l) flat [32256], K=96, N=128. bf16 out only.
// ---------------------------------------------------------------------------
__global__ __launch_bounds__(256)
void embed_mfma(const u16* __restrict__ x16, const u16* __restrict__ cw16,
                const float* __restrict__ cb, const float* __restrict__ pos,
                const float* __restrict__ ttab, const float* __restrict__ stab,
                const int* __restrict__ tidx, const int* __restrict__ sidx,
                u16* __restrict__ h16)
{
    const int t = threadIdx.x;
    const int wave = t >> 6, lane = t & 63;
    const int quad = lane >> 4, l16 = lane & 15;
    const int n0 = wave * 32;

    s16x8 wf[2][3];
    float bv[2];
    #pragma unroll
    for (int nt = 0; nt < 2; ++nt) {
        bv[nt] = cb[n0 + nt * 16 + l16];
        #pragma unroll
        for (int ks = 0; ks < 3; ++ks)
            wf[nt][ks] = *(const s16x8*)&cw16[(n0 + nt * 16 + l16) * 96 + ks * 32 + quad * 8];
    }
    #pragma unroll
    for (int tt = 0; tt < 4; ++tt) {
        const int m0 = (blockIdx.x * 4 + tt) * 16;
        s16x8 af[3];
        #pragma unroll
        for (int ks = 0; ks < 3; ++ks)
            af[ks] = *(const s16x8*)&x16[(size_t)(m0 + l16) * 96 + ks * 32 + quad * 8];
        f32x4 a0 = (f32x4){0.f,0.f,0.f,0.f}, a1 = (f32x4){0.f,0.f,0.f,0.f};
        #pragma unroll
        for (int ks = 0; ks < 3; ++ks) {
            a0 = mfma16(af[ks], wf[0][ks], a0);
            a1 = mfma16(af[ks], wf[1][ks], a1);
        }
        #pragma unroll
        for (int r = 0; r < 4; ++r) {
            int row = m0 + quad * 4 + r;
            int b = row / 252, l = row - b * 252;
            int ti = tidx[row], si = sidx[row];
            size_t tok = (size_t)b * 264 + 12 + l;
            #pragma unroll
            for (int nt = 0; nt < 2; ++nt) {
                int col = n0 + nt * 16 + l16;
                float v = (nt ? a1[r] : a0[r]) + bv[nt]
                        + pos[(12 + l) * 128 + col]
                        + ttab[ti * 128 + col] + stab[si * 128 + col];
                h16[tok * 128 + col] = f2bf(v);
            }
        }
    }
}

// ---------------------------------------------------------------------------
// C = act(A[M,K] @ W[N,K]^T + bias). 64x64 block tile, 4 waves, LDK=136.
// QSCALE: multiply by 0.25*log2(e) when blockIdx.y < 2 (Q cols of qkv).
// QKVL: scatter stores to head-blocked planes Q|K|V [B][H][S][16].
// ---------------------------------------------------------------------------
template<bool RELU, bool QSCALE, bool QKVL>
__global__ __launch_bounds__(256)
void gemm_bias(const u16* __restrict__ A, const u16* __restrict__ W,
               const float* __restrict__ bias, u16* __restrict__ C,
               int N, int K)
{
    const int LDK = 136;
    __shared__ alignas(16) u16 As[64 * 136];
    __shared__ alignas(16) u16 Ws[64 * 136];
    const int m0 = blockIdx.x * 64;
    const int n0 = blockIdx.y * 64;
    const int t = threadIdx.x;
    const int wave = t >> 6, lane = t & 63;
    const int quad = lane >> 4, l16 = lane & 15;
    const int wm = (wave & 1) * 32, wn = (wave >> 1) * 32;

    f32x4 acc[2][2];
    #pragma unroll
    for (int i = 0; i < 2; ++i)
        #pragma unroll
        for (int j = 0; j < 2; ++j) acc[i][j] = (f32x4){0.f, 0.f, 0.f, 0.f};

    for (int kc = 0; kc < K; kc += 128) {
        __syncthreads();
        #pragma unroll
        for (int i = 0; i < 4; ++i) {
            int id = i * 256 + t;
            int row = id >> 4, c8 = (id & 15) << 3;
            *(uint4*)&As[row * LDK + c8] = *(const uint4*)&A[(size_t)(m0 + row) * K + kc + c8];
            *(uint4*)&Ws[row * LDK + c8] = *(const uint4*)&W[(size_t)(n0 + row) * K + kc + c8];
        }
        __syncthreads();
        #pragma unroll
        for (int ks = 0; ks < 4; ++ks) {
            s16x8 a0 = *(const s16x8*)&As[(wm + l16) * LDK + ks * 32 + quad * 8];
            s16x8 a1 = *(const s16x8*)&As[(wm + 16 + l16) * LDK + ks * 32 + quad * 8];
            s16x8 b0 = *(const s16x8*)&Ws[(wn + l16) * LDK + ks * 32 + quad * 8];
            s16x8 b1 = *(const s16x8*)&Ws[(wn + 16 + l16) * LDK + ks * 32 + quad * 8];
            acc[0][0] = mfma16(a0, b0, acc[0][0]);
            acc[0][1] = mfma16(a0, b1, acc[0][1]);
            acc[1][0] = mfma16(a1, b0, acc[1][0]);
            acc[1][1] = mfma16(a1, b1, acc[1][1]);
        }
    }
    #pragma unroll
    for (int ni = 0; ni < 2; ++ni) {
        int col = n0 + wn + ni * 16 + l16;
        float bv = bias[col];
        #pragma unroll
        for (int mi = 0; mi < 2; ++mi) {
            #pragma unroll
            for (int r = 0; r < 4; ++r) {
                int row = m0 + wm + mi * 16 + quad * 4 + r;
                float v = acc[mi][ni][r] + bv;
                if (RELU) v = fmaxf(v, 0.f);
                if (QSCALE && blockIdx.y < 2) v *= 0.360673760222241f; // 0.25*log2(e)
                if (QKVL) {
                    int part = col >> 7, hh = (col >> 4) & 7, d = col & 15;
                    int b = row / 264, s = row - b * 264;
                    C[(size_t)part * PLANE + (size_t)b * 33792 + hh * 4224 + s * 16 + d] = f2bf(v);
                } else {
                    C[(size_t)row * N + col] = f2bf(v);
                }
            }
        }
    }
}

// ---------------------------------------------------------------------------
// Fused: y = LN(A[M,K] @ W[128,K]^T + bias + resid). 64-row block, 4 waves;
// wave owns 16 full rows -> in-wave LN. Residual bf16. W32: fp32 final out.
// ---------------------------------------------------------------------------
template<int K, bool W32>
__global__ __launch_bounds__(256)
void gemm_ln(const u16* __restrict__ A, const u16* __restrict__ W,
             const float* __restrict__ bias, const u16* __restrict__ resid,
             const float* __restrict__ g, const float* __restrict__ be,
             float* o32, u16* o16)
{
    const int LDK = 136;
    __shared__ alignas(16) u16 As[64 * 136];
    __shared__ alignas(16) u16 Ws[128 * 136];
    const int m0 = blockIdx.x * 64;
    const int t = threadIdx.x;
    const int wave = t >> 6, lane = t & 63;
    const int quad = lane >> 4, l16 = lane & 15;
    const int wr = wave * 16;

    f32x4 acc[8];
    #pragma unroll
    for (int i = 0; i < 8; ++i) acc[i] = (f32x4){0.f, 0.f, 0.f, 0.f};

    for (int kc = 0; kc < K; kc += 128) {
        __syncthreads();
        #pragma unroll
        for (int i = 0; i < 4; ++i) {
            int id = i * 256 + t;
            int row = id >> 4, c8 = (id & 15) << 3;
            *(uint4*)&As[row * LDK + c8] = *(const uint4*)&A[(size_t)(m0 + row) * K + kc + c8];
        }
        #pragma unroll
        for (int i = 0; i < 8; ++i) {
            int id = i * 256 + t;
            int row = id >> 4, c8 = (id & 15) << 3;
            *(uint4*)&Ws[row * LDK + c8] = *(const uint4*)&W[(size_t)row * K + kc + c8];
        }
        __syncthreads();
        #pragma unroll
        for (int ks = 0; ks < 4; ++ks) {
            s16x8 a = *(const s16x8*)&As[(wr + l16) * LDK + ks * 32 + quad * 8];
            #pragma unroll
            for (int nt = 0; nt < 8; ++nt) {
                s16x8 b = *(const s16x8*)&Ws[(nt * 16 + l16) * LDK + ks * 32 + quad * 8];
                acc[nt] = mfma16(a, b, acc[nt]);
            }
        }
    }
    #pragma unroll
    for (int nt = 0; nt < 8; ++nt) {
        int col = nt * 16 + l16;
        float bv = bias[col];
        #pragma unroll
        for (int r = 0; r < 4; ++r) {
            int row = m0 + wr + quad * 4 + r;
            acc[nt][r] += bv + bf2f(resid[(size_t)row * 128 + col]);
        }
    }
    float sm[4], sq[4];
    #pragma unroll
    for (int r = 0; r < 4; ++r) {
        float s = 0.f, q = 0.f;
        #pragma unroll
        for (int nt = 0; nt < 8; ++nt) { float v = acc[nt][r]; s += v; q += v * v; }
        sm[r] = s; sq[r] = q;
    }
    #pragma unroll
    for (int mk = 1; mk < 16; mk <<= 1) {
        #pragma unroll
        for (int r = 0; r < 4; ++r) {
            sm[r] += __shfl_xor(sm[r], mk, 64);
            sq[r] += __shfl_xor(sq[r], mk, 64);
        }
    }
    #pragma unroll
    for (int r = 0; r < 4; ++r) {
        float mean = sm[r] * (1.f / 128.f);
        float var = sq[r] * (1.f / 128.f) - mean * mean;
        float rstd = rsqrtf(var + 1e-5f);
        int row = m0 + wr + quad * 4 + r;
        #pragma unroll
        for (int nt = 0; nt < 8; ++nt) {
            int col = nt * 16 + l16;
            float y = (acc[nt][r] - mean) * rstd * g[col] + be[col];
            if (W32) o32[(size_t)row * 128 + col] = y;
            else     o16[(size_t)row * 128 + col] = f2bf(y);
        }
    }
}

// ---------------------------------------------------------------------------
// Attention v6: head-blocked planes, K read DIRECTLY from global (coalesced,
// L2-hot) -- no Ks LDS stage. V transposed in LDS (9.5 KB total). One block
// per (b,h), grid 1024. Transpose-free scores, exp2 softmax, v_perm P.
// ---------------------------------------------------------------------------
__global__ __launch_bounds__(256)
void attn_kernel(const u16* __restrict__ qkv, u16* __restrict__ ctx)
{
    const int STR = 296;  // VT: [d=16][key padded], keys 264..295 zeroed
    __shared__ alignas(16) u16 VT[16 * STR];
    const int b = blockIdx.x >> 3, h = blockIdx.x & 7;
    const u16* qp = qkv + (size_t)(b * 8 + h) * 4224;
    const u16* kp = qp + PLANE;
    const u16* vp = qp + 2 * PLANE;
    const int t = threadIdx.x;
    const int wave = t >> 6, lane = t & 63;
    const int quad = lane >> 4, l16 = lane & 15;
    const int hq = h * 16;

    // V: coalesced uint4 into regs, scalar transpose into VT (stagger halves)
    for (int i = t; i < 528; i += 256) {
        int key = i >> 1, dq = (i & 1) * 8;
        union { uint4 w; u16 u[8]; } vv;
        vv.w = *(const uint4*)&vp[i * 8];
        #pragma unroll
        for (int j = 0; j < 8; ++j) {
            int jj = (i & 1) ? ((j + 4) & 7) : j;
            VT[(dq + jj) * STR + key] = vv.u[jj];
        }
    }
    for (int i = t; i < 16 * 32; i += 256) {
        int d = i >> 5, c = 264 + (i & 31);
        VT[d * STR + c] = 0;
    }
    __syncthreads();

    for (int qt = wave; qt < 17; qt += 4) {
        const int q0 = qt * 16;
        s16x8 qf = (s16x8){0, 0, 0, 0, 0, 0, 0, 0};
        {
            int qrow = q0 + l16;
            if (quad < 2 && qrow < 264)
                qf = *(const s16x8*)&qp[qrow * 16 + quad * 8];
        }
        // scores transposed; K fragments straight from global (16B/lane,
        // 17 independent loads -> vmcnt pipelined)
        f32x4 sc[17];
        #pragma unroll
        for (int kt = 0; kt < 17; ++kt) {
            s16x8 kf = (s16x8){0, 0, 0, 0, 0, 0, 0, 0};
            int krow = kt * 16 + l16;
            if (quad < 2 && krow < 264)
                kf = *(const s16x8*)&kp[krow * 16 + quad * 8];
            f32x4 z = (f32x4){0.f, 0.f, 0.f, 0.f};
            sc[kt] = mfma16(kf, qf, z);
        }
        // softmax in log2 domain (Q pre-scaled); key = kt*16 + quad*4 + r
        float mx = -1e30f;
        #pragma unroll
        for (int kt = 0; kt < 17; ++kt) {
            #pragma unroll
            for (int r = 0; r < 4; ++r) {
                float s = sc[kt][r];
                if (kt == 16 && quad >= 2) s = -1e30f;   // keys >= 264
                sc[kt][r] = s;
                mx = fmaxf(mx, s);
            }
        }
        mx = fmaxf(mx, __shfl_xor(mx, 16, 64));
        mx = fmaxf(mx, __shfl_xor(mx, 32, 64));
        float ls = 0.f;
        #pragma unroll
        for (int kt = 0; kt < 17; ++kt) {
            #pragma unroll
            for (int r = 0; r < 4; ++r) {
                float e = __builtin_amdgcn_exp2f(sc[kt][r] - mx);
                sc[kt][r] = e;
                ls += e;
            }
        }
        ls += __shfl_xor(ls, 16, 64);
        ls += __shfl_xor(ls, 32, 64);
        float rinv = 1.f / ls;
        float rinvT[4];
        #pragma unroll
        for (int r = 0; r < 4; ++r) rinvT[r] = __shfl(rinv, quad * 4 + r, 64);

        // PV: P packed from sc regs via v_perm hi16 truncation
        f32x4 oa = (f32x4){0.f, 0.f, 0.f, 0.f};
        #pragma unroll
        for (int c = 0; c < 9; ++c) {
            const int kt0 = 2 * c, kt1 = 2 * c + 1;
            union { s16x8 v; uint4 w; } pk;
            pk.w.x = __builtin_amdgcn_perm(fbits(sc[kt0][1]), fbits(sc[kt0][0]), 0x07060302u);
            pk.w.y = __builtin_amdgcn_perm(fbits(sc[kt0][3]), fbits(sc[kt0][2]), 0x07060302u);
            if (c == 8) { pk.w.z = 0; pk.w.w = 0; }
            else {
                pk.w.z = __builtin_amdgcn_perm(fbits(sc[kt1][1]), fbits(sc[kt1][0]), 0x07060302u);
                pk.w.w = __builtin_amdgcn_perm(fbits(sc[kt1][3]), fbits(sc[kt1][2]), 0x07060302u);
            }
            union { s16x8 v; uint2 h2[2]; } vt;
            vt.h2[0] = *(const uint2*)&VT[l16 * STR + kt0 * 16 + quad * 4];
            vt.h2[1] = *(const uint2*)&VT[l16 * STR + kt1 * 16 + quad * 4];
            oa = mfma16(pk.v, vt.v, oa);
        }
        #pragma unroll
        for (int r = 0; r < 4; ++r) {
            int row = q0 + quad * 4 + r;
            if (row < 264)
                ctx[((size_t)b * 264 + row) * 128 + hq + l16] = f2bf(oa[r] * rinvT[r]);
        }
    }
}

// ---------------------------------------------------------------------------
extern "C" void kernel_launch(void* const* d_in, const int* in_sizes, int n_in,
                              void* d_out, int out_size, void* d_ws, size_t ws_size,
                              hipStream_t stream)
{
    (void)in_sizes; (void)n_in; (void)out_size; (void)ws_size;
    const float* x    = (const float*)d_in[0];
    const int*   tidx = (const int*)d_in[1];
    const int*   sidx = (const int*)d_in[2];
    const float* cw   = (const float*)d_in[3];
    const float* cb   = (const float*)d_in[4];
    const float* pos  = (const float*)d_in[5];
    const float* ttab = (const float*)d_in[6];
    const float* stab = (const float*)d_in[7];
    const float* cls  = (const float*)d_in[8];
    const float* Wqkv = (const float*)d_in[9];
    const float* bqkv = (const float*)d_in[10];
    const float* Wo   = (const float*)d_in[11];
    const float* bo   = (const float*)d_in[12];
    const float* W1   = (const float*)d_in[13];
    const float* b1   = (const float*)d_in[14];
    const float* W2   = (const float*)d_in[15];
    const float* b2   = (const float*)d_in[16];
    const float* g1   = (const float*)d_in[17];
    const float* be1  = (const float*)d_in[18];
    const float* g2   = (const float*)d_in[19];
    const float* be2  = (const float*)d_in[20];

    // workspace layout (bytes):
    //   h16  [33792,128] bf16 @ 0          ( 8650752)
    //   hA   [33792,128] bf16 @ 8650752    ( 8650752)  LN1 out
    //   big  @ 17301504 (34603008)  qkv planes (25952256) / ff1 [33792,512]; x16 alias
    //   ctx  @ 51904512 (8650752); cw16 alias pre-layer0
    //   bf16 weights @ 60555264: wqkv 1179648 | wo 393216 | w1 1572864 | w2 1572864
    char* ws = (char*)d_ws;
    u16* h16    = (u16*)ws;
    u16* hA     = (u16*)(ws + 8650752);
    u16* big    = (u16*)(ws + 17301504);
    u16* ctx    = (u16*)(ws + 51904512);
    u16* wqkv16 = (u16*)(ws + 60555264);
    u16* wo16   = (u16*)(ws + 61734912);
    u16* w116   = (u16*)(ws + 62128128);
    u16* w216   = (u16*)(ws + 63700992);
    u16* x16    = big;                    // [32256, 96] bf16, free before layer 0
    u16* cw16   = ctx;                    // [128, 96]  bf16, free before layer 0

    cvt_all<<<21360, 256, 0, stream>>>(Wqkv, Wo, W1, W2, cw, x,
                                       wqkv16, wo16, w116, w216, cw16, x16);
    embed_cls_kernel<<<768, 256, 0, stream>>>(cls, pos, h16);
    embed_mfma<<<504, 256, 0, stream>>>(x16, cw16, cb, pos, ttab, stab, tidx, sidx, h16);

    for (int l = 0; l < 12; ++l) {
        gemm_bias<false, true, true><<<dim3(528, 6), 256, 0, stream>>>(
            h16, wqkv16 + l * 384 * 128, bqkv + l * 384, big, 384, 128);
        attn_kernel<<<1024, 256, 0, stream>>>(big, ctx);
        gemm_ln<128, false><<<528, 256, 0, stream>>>(
            ctx, wo16 + l * 128 * 128, bo + l * 128, h16, g1 + l * 128, be1 + l * 128,
            nullptr, hA);
        gemm_bias<true, false, false><<<dim3(528, 8), 256, 0, stream>>>(
            hA, w116 + l * 512 * 128, b1 + l * 512, big, 512, 128);
        if (l == 11) {
            gemm_ln<512, true><<<528, 256, 0, stream>>>(
                big, w216 + l * 128 * 512, b2 + l * 128, hA, g2 + l * 128, be2 + l * 128,
                (float*)d_out, nullptr);
        } else {
            gemm_ln<512, false><<<528, 256, 0, stream>>>(
                big, w216 + l * 128 * 512, b2 + l * 128, hA, g2 + l * 128, be2 + l * 128,
                nullptr, h16);
        }
    }
}

// Round 15
// 1158.135 us; speedup vs baseline: 1.2520x; 1.2520x over previous
//
#include <hip/hip_runtime.h>

typedef unsigned short u16;
typedef __attribute__((ext_vector_type(8))) short s16x8;
typedef __attribute__((ext_vector_type(4))) float f32x4;

__device__ __forceinline__ float bf2f(u16 u) {
    union { unsigned i; float f; } v; v.i = (unsigned)u << 16; return v.f;
}
__device__ __forceinline__ u16 f2bf(float f) {
    union { float f; unsigned i; } v; v.f = f;
    unsigned r = v.i + 0x7fffu + ((v.i >> 16) & 1u);
    return (u16)(r >> 16);
}
__device__ __forceinline__ unsigned fbits(float f) {
    union { float f; unsigned i; } v; v.f = f; return v.i;
}
__device__ __forceinline__ f32x4 mfma16(s16x8 a, s16x8 b, f32x4 c) {
    return __builtin_amdgcn_mfma_f32_16x16x32_bf16(a, b, c, 0, 0, 0);
}

#define PLANE 4325376   // u16 elements per qkv plane: 128*8*264*16

// ---------------------------------------------------------------------------
// One-shot fp32 -> bf16 conversion of all constant tensors (6 segments, each
// a multiple of 256 elements -> block-aligned, fully coalesced).
// ---------------------------------------------------------------------------
__global__ __launch_bounds__(256)
void cvt_all(const float* __restrict__ Wqkv, const float* __restrict__ Wo,
             const float* __restrict__ W1, const float* __restrict__ W2,
             const float* __restrict__ cw, const float* __restrict__ x,
             u16* wq16, u16* wo16, u16* w116, u16* w216, u16* cw16, u16* x16)
{
    int i = blockIdx.x * 256 + threadIdx.x;           // < 5468160
    if (i < 589824)        wq16[i] = f2bf(Wqkv[i]);
    else if (i < 786432)   wo16[i - 589824] = f2bf(Wo[i - 589824]);
    else if (i < 1572864)  w116[i - 786432] = f2bf(W1[i - 786432]);
    else if (i < 2359296)  w216[i - 1572864] = f2bf(W2[i - 1572864]);
    else if (i < 2371584)  cw16[i - 2359296] = f2bf(cw[i - 2359296]);
    else                   x16[i - 2371584] = f2bf(x[i - 2371584]);
}

// ---------------------------------------------------------------------------
// cls rows: h[b, s<12, :] = cls[s] + pos[s]   (bf16 out only)
// ---------------------------------------------------------------------------
__global__ __launch_bounds__(256)
void embed_cls_kernel(const float* __restrict__ cls, const float* __restrict__ pos,
                      u16* __restrict__ h16)
{
    int i = blockIdx.x * 256 + threadIdx.x;           // < 128*12*128
    int e = i & 127, s = (i >> 7) % 12, b = i / (12 * 128);
    float v = cls[s * 128 + e] + pos[s * 128 + e];
    h16[((size_t)b * 264 + s) * 128 + e] = f2bf(v);
}

// ---------------------------------------------------------------------------
// Conv-embed via MFMA: rows = (b,l) flat [32256], K=96, N=128. bf16 out only.
// ---------------------------------------------------------------------------
__global__ __launch_bounds__(256)
void embed_mfma(const u16* __restrict__ x16, const u16* __restrict__ cw16,
                const float* __restrict__ cb, const float* __restrict__ pos,
                const float* __restrict__ ttab, const float* __restrict__ stab,
                const int* __restrict__ tidx, const int* __restrict__ sidx,
                u16* __restrict__ h16)
{
    const int t = threadIdx.x;
    const int wave = t >> 6, lane = t & 63;
    const int quad = lane >> 4, l16 = lane & 15;
    const int n0 = wave * 32;

    s16x8 wf[2][3];
    float bv[2];
    #pragma unroll
    for (int nt = 0; nt < 2; ++nt) {
        bv[nt] = cb[n0 + nt * 16 + l16];
        #pragma unroll
        for (int ks = 0; ks < 3; ++ks)
            wf[nt][ks] = *(const s16x8*)&cw16[(n0 + nt * 16 + l16) * 96 + ks * 32 + quad * 8];
    }
    #pragma unroll
    for (int tt = 0; tt < 4; ++tt) {
        const int m0 = (blockIdx.x * 4 + tt) * 16;
        s16x8 af[3];
        #pragma unroll
        for (int ks = 0; ks < 3; ++ks)
            af[ks] = *(const s16x8*)&x16[(size_t)(m0 + l16) * 96 + ks * 32 + quad * 8];
        f32x4 a0 = (f32x4){0.f,0.f,0.f,0.f}, a1 = (f32x4){0.f,0.f,0.f,0.f};
        #pragma unroll
        for (int ks = 0; ks < 3; ++ks) {
            a0 = mfma16(af[ks], wf[0][ks], a0);
            a1 = mfma16(af[ks], wf[1][ks], a1);
        }
        #pragma unroll
        for (int r = 0; r < 4; ++r) {
            int row = m0 + quad * 4 + r;
            int b = row / 252, l = row - b * 252;
            int ti = tidx[row], si = sidx[row];
            size_t tok = (size_t)b * 264 + 12 + l;
            #pragma unroll
            for (int nt = 0; nt < 2; ++nt) {
                int col = n0 + nt * 16 + l16;
                float v = (nt ? a1[r] : a0[r]) + bv[nt]
                        + pos[(12 + l) * 128 + col]
                        + ttab[ti * 128 + col] + stab[si * 128 + col];
                h16[tok * 128 + col] = f2bf(v);
            }
        }
    }
}

// ---------------------------------------------------------------------------
// C = act(A[M,K] @ W[N,K]^T + bias). 64x64 block tile, 4 waves, LDK=136.
// QSCALE: multiply by 0.25*log2(e) when blockIdx.y < 2 (Q cols of qkv).
// QKVL: scatter stores to head-blocked planes Q|K|V [B][H][S][16].
// ---------------------------------------------------------------------------
template<bool RELU, bool QSCALE, bool QKVL>
__global__ __launch_bounds__(256)
void gemm_bias(const u16* __restrict__ A, const u16* __restrict__ W,
               const float* __restrict__ bias, u16* __restrict__ C,
               int N, int K)
{
    const int LDK = 136;
    __shared__ alignas(16) u16 As[64 * 136];
    __shared__ alignas(16) u16 Ws[64 * 136];
    const int m0 = blockIdx.x * 64;
    const int n0 = blockIdx.y * 64;
    const int t = threadIdx.x;
    const int wave = t >> 6, lane = t & 63;
    const int quad = lane >> 4, l16 = lane & 15;
    const int wm = (wave & 1) * 32, wn = (wave >> 1) * 32;

    f32x4 acc[2][2];
    #pragma unroll
    for (int i = 0; i < 2; ++i)
        #pragma unroll
        for (int j = 0; j < 2; ++j) acc[i][j] = (f32x4){0.f, 0.f, 0.f, 0.f};

    for (int kc = 0; kc < K; kc += 128) {
        __syncthreads();
        #pragma unroll
        for (int i = 0; i < 4; ++i) {
            int id = i * 256 + t;
            int row = id >> 4, c8 = (id & 15) << 3;
            *(uint4*)&As[row * LDK + c8] = *(const uint4*)&A[(size_t)(m0 + row) * K + kc + c8];
            *(uint4*)&Ws[row * LDK + c8] = *(const uint4*)&W[(size_t)(n0 + row) * K + kc + c8];
        }
        __syncthreads();
        #pragma unroll
        for (int ks = 0; ks < 4; ++ks) {
            s16x8 a0 = *(const s16x8*)&As[(wm + l16) * LDK + ks * 32 + quad * 8];
            s16x8 a1 = *(const s16x8*)&As[(wm + 16 + l16) * LDK + ks * 32 + quad * 8];
            s16x8 b0 = *(const s16x8*)&Ws[(wn + l16) * LDK + ks * 32 + quad * 8];
            s16x8 b1 = *(const s16x8*)&Ws[(wn + 16 + l16) * LDK + ks * 32 + quad * 8];
            acc[0][0] = mfma16(a0, b0, acc[0][0]);
            acc[0][1] = mfma16(a0, b1, acc[0][1]);
            acc[1][0] = mfma16(a1, b0, acc[1][0]);
            acc[1][1] = mfma16(a1, b1, acc[1][1]);
        }
    }
    #pragma unroll
    for (int ni = 0; ni < 2; ++ni) {
        int col = n0 + wn + ni * 16 + l16;
        float bv = bias[col];
        #pragma unroll
        for (int mi = 0; mi < 2; ++mi) {
            #pragma unroll
            for (int r = 0; r < 4; ++r) {
                int row = m0 + wm + mi * 16 + quad * 4 + r;
                float v = acc[mi][ni][r] + bv;
                if (RELU) v = fmaxf(v, 0.f);
                if (QSCALE && blockIdx.y < 2) v *= 0.360673760222241f; // 0.25*log2(e)
                if (QKVL) {
                    int part = col >> 7, hh = (col >> 4) & 7, d = col & 15;
                    int b = row / 264, s = row - b * 264;
                    C[(size_t)part * PLANE + (size_t)b * 33792 + hh * 4224 + s * 16 + d] = f2bf(v);
                } else {
                    C[(size_t)row * N + col] = f2bf(v);
                }
            }
        }
    }
}

// ---------------------------------------------------------------------------
// Fused: y = LN(A[M,K] @ W[128,K]^T + bias + resid). 64-row block, 4 waves;
// wave owns 16 full rows -> in-wave LN. Residual bf16. W32: fp32 final out.
// ---------------------------------------------------------------------------
template<int K, bool W32>
__global__ __launch_bounds__(256)
void gemm_ln(const u16* __restrict__ A, const u16* __restrict__ W,
             const float* __restrict__ bias, const u16* __restrict__ resid,
             const float* __restrict__ g, const float* __restrict__ be,
             float* o32, u16* o16)
{
    const int LDK = 136;
    __shared__ alignas(16) u16 As[64 * 136];
    __shared__ alignas(16) u16 Ws[128 * 136];
    const int m0 = blockIdx.x * 64;
    const int t = threadIdx.x;
    const int wave = t >> 6, lane = t & 63;
    const int quad = lane >> 4, l16 = lane & 15;
    const int wr = wave * 16;

    f32x4 acc[8];
    #pragma unroll
    for (int i = 0; i < 8; ++i) acc[i] = (f32x4){0.f, 0.f, 0.f, 0.f};

    for (int kc = 0; kc < K; kc += 128) {
        __syncthreads();
        #pragma unroll
        for (int i = 0; i < 4; ++i) {
            int id = i * 256 + t;
            int row = id >> 4, c8 = (id & 15) << 3;
            *(uint4*)&As[row * LDK + c8] = *(const uint4*)&A[(size_t)(m0 + row) * K + kc + c8];
        }
        #pragma unroll
        for (int i = 0; i < 8; ++i) {
            int id = i * 256 + t;
            int row = id >> 4, c8 = (id & 15) << 3;
            *(uint4*)&Ws[row * LDK + c8] = *(const uint4*)&W[(size_t)row * K + kc + c8];
        }
        __syncthreads();
        #pragma unroll
        for (int ks = 0; ks < 4; ++ks) {
            s16x8 a = *(const s16x8*)&As[(wr + l16) * LDK + ks * 32 + quad * 8];
            #pragma unroll
            for (int nt = 0; nt < 8; ++nt) {
                s16x8 b = *(const s16x8*)&Ws[(nt * 16 + l16) * LDK + ks * 32 + quad * 8];
                acc[nt] = mfma16(a, b, acc[nt]);
            }
        }
    }
    #pragma unroll
    for (int nt = 0; nt < 8; ++nt) {
        int col = nt * 16 + l16;
        float bv = bias[col];
        #pragma unroll
        for (int r = 0; r < 4; ++r) {
            int row = m0 + wr + quad * 4 + r;
            acc[nt][r] += bv + bf2f(resid[(size_t)row * 128 + col]);
        }
    }
    float sm[4], sq[4];
    #pragma unroll
    for (int r = 0; r < 4; ++r) {
        float s = 0.f, q = 0.f;
        #pragma unroll
        for (int nt = 0; nt < 8; ++nt) { float v = acc[nt][r]; s += v; q += v * v; }
        sm[r] = s; sq[r] = q;
    }
    #pragma unroll
    for (int mk = 1; mk < 16; mk <<= 1) {
        #pragma unroll
        for (int r = 0; r < 4; ++r) {
            sm[r] += __shfl_xor(sm[r], mk, 64);
            sq[r] += __shfl_xor(sq[r], mk, 64);
        }
    }
    #pragma unroll
    for (int r = 0; r < 4; ++r) {
        float mean = sm[r] * (1.f / 128.f);
        float var = sq[r] * (1.f / 128.f) - mean * mean;
        float rstd = rsqrtf(var + 1e-5f);
        int row = m0 + wr + quad * 4 + r;
        #pragma unroll
        for (int nt = 0; nt < 8; ++nt) {
            int col = nt * 16 + l16;
            float y = (acc[nt][r] - mean) * rstd * g[col] + be[col];
            if (W32) o32[(size_t)row * 128 + col] = y;
            else     o16[(size_t)row * 128 + col] = f2bf(y);
        }
    }
}

// ---------------------------------------------------------------------------
// Attention v7 (= proven R9 structure + 4-way split softmax chains).
// Head-blocked planes; K staged in LDS (load-once, reuse 17x -- R14 measured
// that direct-global K regresses 45->63 us); V transposed in LDS; grid 1024.
// Transpose-free scores, exp2 softmax, v_perm P pack, deferred 1/l.
// ---------------------------------------------------------------------------
__global__ __launch_bounds__(256)
void attn_kernel(const u16* __restrict__ qkv, u16* __restrict__ ctx)
{
    const int STR = 296;  // VT: [d=16][key padded], keys 264..295 zeroed
    const int KLD = 24;   // Ks: [key=272][d=16 pad 24]
    __shared__ alignas(16) u16 VT[16 * STR];
    __shared__ alignas(16) u16 Ks[272 * KLD];
    const int b = blockIdx.x >> 3, h = blockIdx.x & 7;
    const u16* qp = qkv + (size_t)(b * 8 + h) * 4224;
    const u16* kp = qp + PLANE;
    const u16* vp = qp + 2 * PLANE;
    const int t = threadIdx.x;
    const int wave = t >> 6, lane = t & 63;
    const int quad = lane >> 4, l16 = lane & 15;
    const int hq = h * 16;

    // K: contiguous -> coalesced uint4 into padded LDS rows
    for (int i = t; i < 528; i += 256)
        *(uint4*)&Ks[(i >> 1) * KLD + (i & 1) * 8] = *(const uint4*)&kp[i * 8];
    // V: coalesced uint4 into regs, scalar transpose into VT (stagger halves)
    for (int i = t; i < 528; i += 256) {
        int key = i >> 1, dq = (i & 1) * 8;
        union { uint4 w; u16 u[8]; } vv;
        vv.w = *(const uint4*)&vp[i * 8];
        #pragma unroll
        for (int j = 0; j < 8; ++j) {
            int jj = (i & 1) ? ((j + 4) & 7) : j;
            VT[(dq + jj) * STR + key] = vv.u[jj];
        }
    }
    for (int i = t; i < 16 * 32; i += 256) {
        int d = i >> 5, c = 264 + (i & 31);
        VT[d * STR + c] = 0;
    }
    __syncthreads();

    for (int qt = wave; qt < 17; qt += 4) {
        const int q0 = qt * 16;
        s16x8 qf = (s16x8){0, 0, 0, 0, 0, 0, 0, 0};
        {
            int qrow = q0 + l16;
            if (quad < 2 && qrow < 264)
                qf = *(const s16x8*)&qp[qrow * 16 + quad * 8];
        }
        f32x4 sc[17];
        #pragma unroll
        for (int kt = 0; kt < 17; ++kt) {
            s16x8 kf = (s16x8){0, 0, 0, 0, 0, 0, 0, 0};
            if (quad < 2)
                kf = *(const s16x8*)&Ks[(kt * 16 + l16) * KLD + quad * 8];
            f32x4 z = (f32x4){0.f, 0.f, 0.f, 0.f};
            sc[kt] = mfma16(kf, qf, z);
        }
        // softmax in log2 domain (Q pre-scaled); key = kt*16 + quad*4 + r.
        // 4 independent accumulator chains (r) -> dep chain 17+2 not 68.
        float mx4[4] = {-1e30f, -1e30f, -1e30f, -1e30f};
        #pragma unroll
        for (int kt = 0; kt < 17; ++kt) {
            #pragma unroll
            for (int r = 0; r < 4; ++r) {
                float s = sc[kt][r];
                if (kt == 16 && quad >= 2) s = -1e30f;   // keys >= 264
                sc[kt][r] = s;
                mx4[r] = fmaxf(mx4[r], s);
            }
        }
        float mx = fmaxf(fmaxf(mx4[0], mx4[1]), fmaxf(mx4[2], mx4[3]));
        mx = fmaxf(mx, __shfl_xor(mx, 16, 64));
        mx = fmaxf(mx, __shfl_xor(mx, 32, 64));
        float ls4[4] = {0.f, 0.f, 0.f, 0.f};
        #pragma unroll
        for (int kt = 0; kt < 17; ++kt) {
            #pragma unroll
            for (int r = 0; r < 4; ++r) {
                float e = __builtin_amdgcn_exp2f(sc[kt][r] - mx);
                sc[kt][r] = e;
                ls4[r] += e;
            }
        }
        float ls = (ls4[0] + ls4[1]) + (ls4[2] + ls4[3]);
        ls += __shfl_xor(ls, 16, 64);
        ls += __shfl_xor(ls, 32, 64);
        float rinv = 1.f / ls;
        float rinvT[4];
        #pragma unroll
        for (int r = 0; r < 4; ++r) rinvT[r] = __shfl(rinv, quad * 4 + r, 64);

        // PV: P packed from sc regs via v_perm hi16 truncation
        f32x4 oa = (f32x4){0.f, 0.f, 0.f, 0.f};
        #pragma unroll
        for (int c = 0; c < 9; ++c) {
            const int kt0 = 2 * c, kt1 = 2 * c + 1;
            union { s16x8 v; uint4 w; } pk;
            pk.w.x = __builtin_amdgcn_perm(fbits(sc[kt0][1]), fbits(sc[kt0][0]), 0x07060302u);
            pk.w.y = __builtin_amdgcn_perm(fbits(sc[kt0][3]), fbits(sc[kt0][2]), 0x07060302u);
            if (c == 8) { pk.w.z = 0; pk.w.w = 0; }
            else {
                pk.w.z = __builtin_amdgcn_perm(fbits(sc[kt1][1]), fbits(sc[kt1][0]), 0x07060302u);
                pk.w.w = __builtin_amdgcn_perm(fbits(sc[kt1][3]), fbits(sc[kt1][2]), 0x07060302u);
            }
            union { s16x8 v; uint2 h2[2]; } vt;
            vt.h2[0] = *(const uint2*)&VT[l16 * STR + kt0 * 16 + quad * 4];
            vt.h2[1] = *(const uint2*)&VT[l16 * STR + kt1 * 16 + quad * 4];
            oa = mfma16(pk.v, vt.v, oa);
        }
        #pragma unroll
        for (int r = 0; r < 4; ++r) {
            int row = q0 + quad * 4 + r;
            if (row < 264)
                ctx[((size_t)b * 264 + row) * 128 + hq + l16] = f2bf(oa[r] * rinvT[r]);
        }
    }
}

// ---------------------------------------------------------------------------
extern "C" void kernel_launch(void* const* d_in, const int* in_sizes, int n_in,
                              void* d_out, int out_size, void* d_ws, size_t ws_size,
                              hipStream_t stream)
{
    (void)in_sizes; (void)n_in; (void)out_size; (void)ws_size;
    const float* x    = (const float*)d_in[0];
    const int*   tidx = (const int*)d_in[1];
    const int*   sidx = (const int*)d_in[2];
    const float* cw   = (const float*)d_in[3];
    const float* cb   = (const float*)d_in[4];
    const float* pos  = (const float*)d_in[5];
    const float* ttab = (const float*)d_in[6];
    const float* stab = (const float*)d_in[7];
    const float* cls  = (const float*)d_in[8];
    const float* Wqkv = (const float*)d_in[9];
    const float* bqkv = (const float*)d_in[10];
    const float* Wo   = (const float*)d_in[11];
    const float* bo   = (const float*)d_in[12];
    const float* W1   = (const float*)d_in[13];
    const float* b1   = (const float*)d_in[14];
    const float* W2   = (const float*)d_in[15];
    const float* b2   = (const float*)d_in[16];
    const float* g1   = (const float*)d_in[17];
    const float* be1  = (const float*)d_in[18];
    const float* g2   = (const float*)d_in[19];
    const float* be2  = (const float*)d_in[20];

    // workspace layout (bytes):
    //   h16  [33792,128] bf16 @ 0          ( 8650752)
    //   hA   [33792,128] bf16 @ 8650752    ( 8650752)  LN1 out
    //   big  @ 17301504 (34603008)  qkv planes (25952256) / ff1 [33792,512]; x16 alias
    //   ctx  @ 51904512 (8650752); cw16 alias pre-layer0
    //   bf16 weights @ 60555264: wqkv 1179648 | wo 393216 | w1 1572864 | w2 1572864
    char* ws = (char*)d_ws;
    u16* h16    = (u16*)ws;
    u16* hA     = (u16*)(ws + 8650752);
    u16* big    = (u16*)(ws + 17301504);
    u16* ctx    = (u16*)(ws + 51904512);
    u16* wqkv16 = (u16*)(ws + 60555264);
    u16* wo16   = (u16*)(ws + 61734912);
    u16* w116   = (u16*)(ws + 62128128);
    u16* w216   = (u16*)(ws + 63700992);
    u16* x16    = big;                    // [32256, 96] bf16, free before layer 0
    u16* cw16   = ctx;                    // [128, 96]  bf16, free before layer 0

    cvt_all<<<21360, 256, 0, stream>>>(Wqkv, Wo, W1, W2, cw, x,
                                       wqkv16, wo16, w116, w216, cw16, x16);
    embed_cls_kernel<<<768, 256, 0, stream>>>(cls, pos, h16);
    embed_mfma<<<504, 256, 0, stream>>>(x16, cw16, cb, pos, ttab, stab, tidx, sidx, h16);

    for (int l = 0; l < 12; ++l) {
        gemm_bias<false, true, true><<<dim3(528, 6), 256, 0, stream>>>(
            h16, wqkv16 + l * 384 * 128, bqkv + l * 384, big, 384, 128);
        attn_kernel<<<1024, 256, 0, stream>>>(big, ctx);
        gemm_ln<128, false><<<528, 256, 0, stream>>>(
            ctx, wo16 + l * 128 * 128, bo + l * 128, h16, g1 + l * 128, be1 + l * 128,
            nullptr, hA);
        gemm_bias<true, false, false><<<dim3(528, 8), 256, 0, stream>>>(
            hA, w116 + l * 512 * 128, b1 + l * 512, big, 512, 128);
        if (l == 11) {
            gemm_ln<512, true><<<528, 256, 0, stream>>>(
                big, w216 + l * 128 * 512, b2 + l * 128, hA, g2 + l * 128, be2 + l * 128,
                (float*)d_out, nullptr);
        } else {
            gemm_ln<512, false><<<528, 256, 0, stream>>>(
                big, w216 + l * 128 * 512, b2 + l * 128, hA, g2 + l * 128, be2 + l * 128,
                nullptr, h16);
        }
    }
}